// Round 6
// baseline (46.444 us; speedup 1.0000x reference)
//
#include <hip/hip_runtime.h>

// NMS2d, x: (8,16,512,512) f32. out = x where x > max of 8 neighbors (replicate pad).
// Round 6: 16 output rows x 4 cols per thread (64 px). 18 float4 loads + 16
// nontemporal float4 stores per thread. Halo columns via __shfl.

#define IMG_H 512
#define IMG_W 512
#define W4 (IMG_W / 4)   // 128 float4 groups per row
#define RPT 16           // rows per thread
#define NR (RPT + 2)     // loaded rows incl. top/bottom halo

typedef float f4 __attribute__((ext_vector_type(4)));

__global__ __launch_bounds__(256) void nms2d_kernel(const float* __restrict__ x,
                                                    float* __restrict__ out,
                                                    int total) {
    int tid = blockIdx.x * blockDim.x + threadIdx.x;
    if (tid >= total) return;

    // tid -> (bc, yt, wx); wx fastest. Rows y0..y0+15, cols 4*wx..4*wx+3.
    int wx   = tid & (W4 - 1);
    int rest = tid >> 7;
    int yt   = rest & (IMG_H / RPT - 1);   // 32 row-groups per image
    int bc   = rest >> 5;
    int y0   = yt << 4;

    const float* img  = x   + (size_t)bc * (IMG_H * IMG_W);
    float*       oimg = out + (size_t)bc * (IMG_H * IMG_W);
    int col = wx << 2;

    int ridx[NR];
    ridx[0] = (y0 > 0) ? y0 - 1 : 0;                         // replicate pad
#pragma unroll
    for (int r = 1; r <= RPT; ++r) ridx[r] = y0 + r - 1;
    ridx[NR - 1] = (y0 + RPT < IMG_H) ? y0 + RPT : IMG_H - 1;

    int lane = threadIdx.x & 63;
    bool waveL = (lane == 0);    // left halo not in this wave
    bool waveR = (lane == 63);   // right halo not in this wave

    f4 rows[NR];
#pragma unroll
    for (int r = 0; r < NR; ++r)
        rows[r] = *(const f4*)(img + (size_t)ridx[r] * IMG_W + col);

    // 6-wide windows per row: [L, x0, x1, x2, x3, R]
    float v[NR][6];
#pragma unroll
    for (int r = 0; r < NR; ++r) {
        float lv = __shfl_up(rows[r].w, 1);
        float rv = __shfl_down(rows[r].x, 1);
        if (waveL)
            lv = (wx == 0) ? rows[r].x : img[(size_t)ridx[r] * IMG_W + col - 1];
        if (waveR)
            rv = (wx == W4 - 1) ? rows[r].w : img[(size_t)ridx[r] * IMG_W + col + 4];
        v[r][0] = lv;
        v[r][1] = rows[r].x; v[r][2] = rows[r].y;
        v[r][3] = rows[r].z; v[r][4] = rows[r].w;
        v[r][5] = rv;
    }

    // horizontal max-of-3 per row
    float h3[NR][4];
#pragma unroll
    for (int r = 0; r < NR; ++r)
#pragma unroll
        for (int k = 0; k < 4; ++k)
            h3[r][k] = fmaxf(fmaxf(v[r][k], v[r][k + 1]), v[r][k + 2]);

    // output rows: centers are v[1..RPT]; top/bottom h3 of r-1, r+1
#pragma unroll
    for (int r = 1; r <= RPT; ++r) {
        f4 o;
#pragma unroll
        for (int k = 0; k < 4; ++k) {
            float m = fmaxf(fmaxf(h3[r - 1][k], h3[r + 1][k]),
                            fmaxf(v[r][k], v[r][k + 2]));
            float c = v[r][k + 1];
            o[k] = (c > m) ? c : 0.0f;
        }
        __builtin_nontemporal_store(o,
            (f4*)(oimg + (size_t)(y0 + r - 1) * IMG_W + col));
    }
}

extern "C" void kernel_launch(void* const* d_in, const int* in_sizes, int n_in,
                              void* d_out, int out_size, void* d_ws, size_t ws_size,
                              hipStream_t stream) {
    const float* x = (const float*)d_in[0];
    float* out = (float*)d_out;
    int total = in_sizes[0] / (4 * RPT);     // 64 px per thread = 262,144
    int block = 256;
    int grid = (total + block - 1) / block;  // 1024 blocks
    nms2d_kernel<<<grid, block, 0, stream>>>(x, out, total);
}

// Round 7
// 45.663 us; speedup vs baseline: 1.0171x; 1.0171x over previous
//
#include <hip/hip_runtime.h>

// NMS2d, x: (8,16,512,512) f32. out = x where x > max of 8 neighbors (replicate pad).
// Round 7: REVERT to round-5 config (best measured: 45.6us, 93.5% of copy BW).
// 8 output rows x 4 cols per thread (32 px). 10 float4 loads + 8 nontemporal
// float4 stores per thread. Halo columns via __shfl.
// RPT=4: 46.9us; RPT=8: 45.6us; RPT=16: 46.4us (occupancy 25%, too few blocks).

#define IMG_H 512
#define IMG_W 512
#define W4 (IMG_W / 4)   // 128 float4 groups per row
#define RPT 8            // rows per thread
#define NR (RPT + 2)     // loaded rows incl. top/bottom halo

typedef float f4 __attribute__((ext_vector_type(4)));

__global__ __launch_bounds__(256) void nms2d_kernel(const float* __restrict__ x,
                                                    float* __restrict__ out,
                                                    int total) {
    int tid = blockIdx.x * blockDim.x + threadIdx.x;
    if (tid >= total) return;

    // tid -> (bc, yt, wx); wx fastest. Rows y0..y0+7, cols 4*wx..4*wx+3.
    int wx   = tid & (W4 - 1);
    int rest = tid >> 7;
    int yt   = rest & (IMG_H / RPT - 1);   // 64 row-octets per image
    int bc   = rest >> 6;
    int y0   = yt << 3;

    const float* img  = x   + (size_t)bc * (IMG_H * IMG_W);
    float*       oimg = out + (size_t)bc * (IMG_H * IMG_W);
    int col = wx << 2;

    int ridx[NR];
    ridx[0] = (y0 > 0) ? y0 - 1 : 0;                         // replicate pad
#pragma unroll
    for (int r = 1; r <= RPT; ++r) ridx[r] = y0 + r - 1;
    ridx[NR - 1] = (y0 + RPT < IMG_H) ? y0 + RPT : IMG_H - 1;

    int lane = threadIdx.x & 63;
    bool waveL = (lane == 0);    // left halo not in this wave
    bool waveR = (lane == 63);   // right halo not in this wave

    f4 rows[NR];
#pragma unroll
    for (int r = 0; r < NR; ++r)
        rows[r] = *(const f4*)(img + (size_t)ridx[r] * IMG_W + col);

    // 6-wide windows per row: [L, x0, x1, x2, x3, R]
    float v[NR][6];
#pragma unroll
    for (int r = 0; r < NR; ++r) {
        float lv = __shfl_up(rows[r].w, 1);
        float rv = __shfl_down(rows[r].x, 1);
        if (waveL)
            lv = (wx == 0) ? rows[r].x : img[(size_t)ridx[r] * IMG_W + col - 1];
        if (waveR)
            rv = (wx == W4 - 1) ? rows[r].w : img[(size_t)ridx[r] * IMG_W + col + 4];
        v[r][0] = lv;
        v[r][1] = rows[r].x; v[r][2] = rows[r].y;
        v[r][3] = rows[r].z; v[r][4] = rows[r].w;
        v[r][5] = rv;
    }

    // horizontal max-of-3 per row
    float h3[NR][4];
#pragma unroll
    for (int r = 0; r < NR; ++r)
#pragma unroll
        for (int k = 0; k < 4; ++k)
            h3[r][k] = fmaxf(fmaxf(v[r][k], v[r][k + 1]), v[r][k + 2]);

    // output rows: centers are v[1..RPT]; top/bottom h3 of r-1, r+1
#pragma unroll
    for (int r = 1; r <= RPT; ++r) {
        f4 o;
#pragma unroll
        for (int k = 0; k < 4; ++k) {
            float m = fmaxf(fmaxf(h3[r - 1][k], h3[r + 1][k]),
                            fmaxf(v[r][k], v[r][k + 2]));
            float c = v[r][k + 1];
            o[k] = (c > m) ? c : 0.0f;
        }
        __builtin_nontemporal_store(o,
            (f4*)(oimg + (size_t)(y0 + r - 1) * IMG_W + col));
    }
}

extern "C" void kernel_launch(void* const* d_in, const int* in_sizes, int n_in,
                              void* d_out, int out_size, void* d_ws, size_t ws_size,
                              hipStream_t stream) {
    const float* x = (const float*)d_in[0];
    float* out = (float*)d_out;
    int total = in_sizes[0] / (4 * RPT);     // 32 px per thread = 524,288
    int block = 256;
    int grid = (total + block - 1) / block;  // 2048 blocks
    nms2d_kernel<<<grid, block, 0, stream>>>(x, out, total);
}